// Round 12
// baseline (185.282 us; speedup 1.0000x reference)
//
#include <hip/hip_runtime.h>
#include <hip/hip_bf16.h>

// Problem dims (fixed by the reference)
constexpr int B_  = 4;
constexpr int S_  = 2048;
constexpr int D_  = 512;
constexpr int H_  = 8;
constexpr int HD_ = 64;
constexpr int M_  = B_ * S_;   // 8192

constexpr float LOG2E = 1.4426950408889634f;

typedef __attribute__((ext_vector_type(8))) short short8v;            // 8 bf16 (4 VGPR) MFMA operand
typedef __attribute__((ext_vector_type(8))) _Float16 half8v;          // 8 f16 (4 VGPR) MFMA operand
typedef __attribute__((ext_vector_type(8))) unsigned short ushort8v;  // 16B staging chunk
typedef __attribute__((ext_vector_type(4))) float float4v;            // 16x16 MFMA C/D
typedef __attribute__((ext_vector_type(16))) float float16v;          // 32x32 MFMA C/D

__device__ __forceinline__ unsigned short f2bf(float x) {  // RNE fp32->bf16
    unsigned u = __builtin_bit_cast(unsigned, x);
    u += 0x7fffu + ((u >> 16) & 1u);
    return (unsigned short)(u >> 16);
}
__device__ __forceinline__ float bf2f(unsigned short h) {
    return __builtin_bit_cast(float, ((unsigned)h) << 16);
}
__device__ __forceinline__ unsigned short f2h(float x) {   // RNE fp32->fp16 bits
    return __builtin_bit_cast(unsigned short, (_Float16)x);
}
__device__ __forceinline__ float fast_exp2(float x) {
#if __has_builtin(__builtin_amdgcn_exp2f)
    return __builtin_amdgcn_exp2f(x);
#else
    return exp2f(x);
#endif
}
// pack two f32 as [trunc-bf16(lo) | trunc-bf16(hi)<<16]  (1 v_perm)
__device__ __forceinline__ unsigned pack_bf16_trunc(float lo, float hi) {
    const unsigned ulo = __builtin_bit_cast(unsigned, lo);
    const unsigned uhi = __builtin_bit_cast(unsigned, hi);
#if __has_builtin(__builtin_amdgcn_perm)
    return __builtin_amdgcn_perm(uhi, ulo, 0x07060302u);
#else
    return (uhi & 0xffff0000u) | (ulo >> 16);
#endif
}
// async global->LDS, 16B per lane; lds dest = wave-uniform base + lane*16
__device__ __forceinline__ void gload_lds16(const void* g, void* lds) {
    __builtin_amdgcn_global_load_lds((const __attribute__((address_space(1))) unsigned*)g,
                                     (__attribute__((address_space(3))) unsigned*)lds, 16, 0, 0);
}

// ---------------------------------------------------------------------------
// Prepass: build bf16 operands.
//   Xp  [8192][1024]: cols [0:512)=hi(x), [512:1024)=lo(x)
//   Wh  [1536][512] : hi(w_qkv);  Wlq [512][512]: lo(w_q);  Wob: hi(w_out)
// ---------------------------------------------------------------------------
__global__ __launch_bounds__(256) void prepass(const float* __restrict__ x,
                                               const float* __restrict__ wqkv,
                                               const float* __restrict__ wout,
                                               unsigned short* __restrict__ Xp,
                                               unsigned short* __restrict__ Wh,
                                               unsigned short* __restrict__ Wlq,
                                               unsigned short* __restrict__ Wob) {
    const int bid = blockIdx.x, t = threadIdx.x;
    if (bid < 2048) {                      // x
        const int flat = bid * 256 + t;
        const int m = flat >> 6, c = (flat & 63) * 8;
        const float4 a = *(const float4*)&x[(size_t)m * 512 + c];
        const float4 b = *(const float4*)&x[(size_t)m * 512 + c + 4];
        const float v[8] = {a.x, a.y, a.z, a.w, b.x, b.y, b.z, b.w};
        ushort8v hi, lo;
#pragma unroll
        for (int i = 0; i < 8; ++i) {
            const unsigned short h = f2bf(v[i]);
            hi[i] = h; lo[i] = f2bf(v[i] - bf2f(h));
        }
        *(ushort8v*)&Xp[(size_t)m * 1024 + c]       = hi;
        *(ushort8v*)&Xp[(size_t)m * 1024 + 512 + c] = lo;
    } else if (bid < 2048 + 384) {         // w_qkv
        const int flat = (bid - 2048) * 256 + t;
        const int e = flat >> 6, c = (flat & 63) * 8;
        const float4 a = *(const float4*)&wqkv[(size_t)e * 512 + c];
        const float4 b = *(const float4*)&wqkv[(size_t)e * 512 + c + 4];
        const float v[8] = {a.x, a.y, a.z, a.w, b.x, b.y, b.z, b.w};
        ushort8v hi, lo;
#pragma unroll
        for (int i = 0; i < 8; ++i) {
            const unsigned short h = f2bf(v[i]);
            hi[i] = h; lo[i] = f2bf(v[i] - bf2f(h));
        }
        *(ushort8v*)&Wh[(size_t)e * 512 + c] = hi;
        if (e < 512) *(ushort8v*)&Wlq[(size_t)e * 512 + c] = lo;
    } else {                               // w_out
        const int flat = (bid - 2432) * 256 + t;
        const int e = flat >> 6, c = (flat & 63) * 8;
        const float4 a = *(const float4*)&wout[(size_t)e * 512 + c];
        const float4 b = *(const float4*)&wout[(size_t)e * 512 + c + 4];
        const float v[8] = {a.x, a.y, a.z, a.w, b.x, b.y, b.z, b.w};
        ushort8v hi;
#pragma unroll
        for (int i = 0; i < 8; ++i) hi[i] = f2bf(v[i]);
        *(ushort8v*)&Wob[(size_t)e * 512 + c] = hi;
    }
}

// ---------------------------------------------------------------------------
// GEMM1 (QKV projection): 128x128 tiles, BK=64, dbuf+prefetch, XCD swizzle,
// fused-Q (K=1536 single f32 accumulation, f16 store pre-scaled by log2e).
// Slices: x>>2 = 0:q(24 iters) 1:k 2:v (8 iters); e0=(x&3)*128. Grid (12,64).
// K stored f16; V stored bf16 with j-bits 2<->3 swapped per 16-group.
// ---------------------------------------------------------------------------
__global__ __launch_bounds__(256, 2) void gemm_qkv(const unsigned short* __restrict__ Xp,
                                                   const unsigned short* __restrict__ Wh,
                                                   const unsigned short* __restrict__ Wlq,
                                                   unsigned short* __restrict__ Qf,
                                                   unsigned short* __restrict__ KH,
                                                   unsigned short* __restrict__ VT) {
    __shared__ unsigned short Asm[2][128 * 64];   // 32 KB
    __shared__ unsigned short Bsm[2][128 * 64];   // 32 KB
    const int t = threadIdx.x, wv = t >> 6, lane = t & 63;
    const int fm = lane & 15, fq = lane >> 4;
    const int bid0 = blockIdx.x + 12 * blockIdx.y;
    const int xcd = bid0 & 7, ii = bid0 >> 3;       // ii in 0..95
    const int x  = ii % 12;
    const int m0 = ((ii / 12) * 8 + xcd) * 128;
    const int slice = x >> 2;            // 0=q 1=k 2=v
    const int e0 = (x & 3) * 128;        // within the 512-wide segment
    const bool vblk = (slice == 2);
    const int kiters = (slice == 0) ? 24 : 8;
    const int wrow = (wv >> 1) * 64, wcol = (wv & 1) * 64;

    const unsigned short* BbaseWh =
        Wh + (size_t)(e0 + (slice == 1 ? 512 : (slice == 2 ? 1024 : 0))) * 512;
    const unsigned short* BbaseWlq = Wlq + (size_t)e0 * 512;

    const int srow = t >> 3;     // 0..31; +32*i extends
    const int skb0 = t & 7;

    float4v acc[4][4];
#pragma unroll
    for (int i = 0; i < 4; ++i)
#pragma unroll
        for (int j = 0; j < 4; ++j) acc[i][j] = (float4v){0.f, 0.f, 0.f, 0.f};

    // prologue: stage tile kk=0 (pass 0: A=XH, B=Wh) into buf 0
    {
#pragma unroll
        for (int i = 0; i < 4; ++i) {
            const int row = srow + 32 * i;
            const int kb = skb0 ^ (row & 7);
            gload_lds16(Xp + (size_t)(m0 + row) * 1024 + kb * 8,
                        &Asm[0][(wv * 64 + 256 * i) * 8]);
            gload_lds16(BbaseWh + (size_t)row * 512 + kb * 8,
                        &Bsm[0][(wv * 64 + 256 * i) * 8]);
        }
    }

    for (int kk = 0; kk < kiters; ++kk) {
        __syncthreads();   // tile kk DMA complete; buf[(kk+1)&1] free

        if (kk + 1 < kiters) {     // prefetch tile kk+1 (overlaps compute of kk)
            const int nk = kk + 1;
            const int pass = nk >> 3;                 // q: 0=XH@Wh 1=XL@Wh 2=XH@Wlq
            const int k0n = (nk & 7) * 64;
            const int nbuf = nk & 1;
            const int aoff = (slice == 0 && pass == 1) ? 512 : 0;
            const unsigned short* Bp = (slice == 0 && pass == 2) ? BbaseWlq : BbaseWh;
#pragma unroll
            for (int i = 0; i < 4; ++i) {
                const int row = srow + 32 * i;
                const int kb = skb0 ^ (row & 7);
                gload_lds16(Xp + (size_t)(m0 + row) * 1024 + aoff + k0n + kb * 8,
                            &Asm[nbuf][(wv * 64 + 256 * i) * 8]);
                gload_lds16(Bp + (size_t)row * 512 + k0n + kb * 8,
                            &Bsm[nbuf][(wv * 64 + 256 * i) * 8]);
            }
        }

        const int buf = kk & 1;
#pragma unroll
        for (int ks = 0; ks < 2; ++ks) {
            short8v af[4], bf[4];
#pragma unroll
            for (int mt = 0; mt < 4; ++mt) {
                const int row = wrow + mt * 16 + fm;
                af[mt] = *(const short8v*)&Asm[buf][row * 64 + 8 * ((4 * ks + fq) ^ (row & 7))];
            }
#pragma unroll
            for (int nt = 0; nt < 4; ++nt) {
                const int row = wcol + nt * 16 + fm;
                bf[nt] = *(const short8v*)&Bsm[buf][row * 64 + 8 * ((4 * ks + fq) ^ (row & 7))];
            }
            if (vblk) {
#pragma unroll
                for (int mt = 0; mt < 4; ++mt)
#pragma unroll
                    for (int nt = 0; nt < 4; ++nt)
                        acc[mt][nt] = __builtin_amdgcn_mfma_f32_16x16x32_bf16(bf[nt], af[mt], acc[mt][nt], 0, 0, 0);
            } else {
#pragma unroll
                for (int mt = 0; mt < 4; ++mt)
#pragma unroll
                    for (int nt = 0; nt < 4; ++nt)
                        acc[mt][nt] = __builtin_amdgcn_mfma_f32_16x16x32_bf16(af[mt], bf[nt], acc[mt][nt], 0, 0, 0);
            }
        }
    }

    if (!vblk) {
        // q: f16 store pre-scaled by log2e; k: f16 store
        unsigned short* __restrict__ dst = (slice == 0) ? Qf : KH;
        const float sc = (slice == 0) ? LOG2E : 1.0f;
#pragma unroll
        for (int mt = 0; mt < 4; ++mt)
#pragma unroll
            for (int nt = 0; nt < 4; ++nt) {
                const int e = e0 + wcol + nt * 16 + fm;
                const int h = e >> 6, hd = e & 63;
#pragma unroll
                for (int r = 0; r < 4; ++r) {
                    const int m = m0 + wrow + mt * 16 + 4 * fq + r;
                    const int b = m >> 11, s = m & 2047;
                    dst[((size_t)(b * 8 + h) * 2048 + s) * 64 + hd] =
                        f2h(acc[mt][nt][r] * sc);
                }
            }
    } else {
        // v: acc rows = e (4fq+r), cols = m (fm);
        // store at j-permuted column s2 (swap bits 2<->3 within 16-group)
#pragma unroll
        for (int nt = 0; nt < 4; ++nt)
#pragma unroll
            for (int r = 0; r < 4; ++r) {
                const int e = e0 + wcol + nt * 16 + 4 * fq + r;
                const int h = e >> 6, hd = e & 63;
#pragma unroll
                for (int mt = 0; mt < 4; ++mt) {
                    const int m = m0 + wrow + mt * 16 + fm;
                    const int b = m >> 11, s = m & 2047;
                    const int s2 = (s & ~12) | ((s & 4) << 1) | ((s & 8) >> 1);
                    VT[((size_t)(b * 8 + h) * 64 + hd) * 2048 + s2] = f2bf(acc[mt][nt][r]);
                }
            }
    }
}

// ---------------------------------------------------------------------------
// MFMA flash attention v13 = v7 pipeline, V read DIRECT from global (L2).
// R11 post-mortem: attn pinned at 46us; LDS-port accounting shows ~74% busy
// (per block-phase: 4 waves x 16 ds_read_b128 + 32KB DMA + 4-way-conflict
// residue). K/V are L2-resident (FETCH 12.3MB) -- per Common-mistake #7 /
// m169 (+26% dropping V-staging when L2-fit), V staging is pure overhead:
//  - Vs eliminated (LDS 32->16 KB); V frags loaded straight from VT (L2)
//    into registers at the TOP of each phase (QK+exp2 ~1500cyc covers the
//    ~200cyc L2 latency). No swizzle needed (bank conflicts are LDS-only);
//    j-permuted VT makes the PV B-frag one contiguous 16B load per lane.
//  - LDS reads/wave-phase 16->8 b128, DMA 4->2, conflicts ~halve.
// K keeps the proven LDS pipeline (A-operand, consumed earliest).
// ---------------------------------------------------------------------------
__global__ __launch_bounds__(256, 2) void attn(const unsigned short* __restrict__ Qfp,
                                               const unsigned short* __restrict__ KHp,
                                               const unsigned short* __restrict__ VTp,
                                               unsigned short* __restrict__ OB) {
    __shared__ unsigned short Ks[2][64 * 64];    // 16 KB, f16 K tiles [j][d], XOR-swizzled
    const int t = threadIdx.x, wv = t >> 6, lane = t & 63;
    const int lq = lane & 31;     // q (and d/j) index within 32
    const int hf2 = lane >> 5;    // half-wave
    // XCD swizzle: 512 blocks, xcd = bid%8; each XCD owns 4 bh (K/V L2-hot)
    const int bid0 = blockIdx.x + 16 * blockIdx.y;
    const int xcd = bid0 & 7, ii = bid0 >> 3;    // ii in 0..63
    const int bh = (ii & 3) * 8 + xcd;
    const int q0 = (ii >> 2) * 128;

    const unsigned short* qfp = Qfp + (size_t)bh * S_ * 64;
    const unsigned short* kh  = KHp + (size_t)bh * S_ * 64;
    const unsigned short* vt  = VTp + (size_t)bh * 64 * S_;

    const int srow = t >> 3;     // 0..31
    const int skb0 = t & 7;

// stage K tile N (64 rows of 64 f16) into Ks[B]; wave wv covers rows 8wv..+7, +32
#define STAGE_K(N, B) do {                                                      \
    _Pragma("unroll")                                                           \
    for (int i_ = 0; i_ < 2; ++i_) {                                            \
        const int row_ = srow + 32 * i_;                                        \
        const int kb_ = skb0 ^ (row_ & 7);                                      \
        gload_lds16(kh + (size_t)((N) * 64 + row_) * 64 + kb_ * 8,              \
                    &Ks[B][(wv * 64 + 256 * i_) * 8]);                          \
    } } while (0)

// load V tile N DIRECT from global (L2-resident) into 8 b128 regs:
// lane reads V^T[d = db*32+lq][j-perm cols (2*jc+hf2)*8 .. +7] of tile N.
// (matches the old Vs read: swizzle was LDS-bank-only; global needs none)
#define LOADV(VR, N) do {                                                       \
    _Pragma("unroll")                                                           \
    for (int jc_ = 0; jc_ < 4; ++jc_)                                           \
        _Pragma("unroll")                                                       \
        for (int db_ = 0; db_ < 2; ++db_)                                       \
            VR[jc_][db_] = *(const short8v*)&vt[(size_t)(db_ * 32 + lq) * S_ +  \
                                                (N) * 64 + (2 * jc_ + hf2) * 8];\
    } while (0)

// QK^T for one tile from Ks[KR] into SN (zeroed here):
// lane (lq,hf2) reg 4g+r of SN[jb] = S[q=lq][j = jb*32 + r + 8g + 4*hf2]
#define QK_STEP(SN, KR) do {                                                    \
    _Pragma("unroll")                                                           \
    for (int jb_ = 0; jb_ < 2; ++jb_)                                           \
        _Pragma("unroll")                                                       \
        for (int r_ = 0; r_ < 16; ++r_) SN[jb_][r_] = 0.f;                      \
    _Pragma("unroll")                                                           \
    for (int kk_ = 0; kk_ < 4; ++kk_)                                           \
        _Pragma("unroll")                                                       \
        for (int jb_ = 0; jb_ < 2; ++jb_) {                                     \
            const int row_ = jb_ * 32 + lq;                                     \
            const int cb_ = 2 * kk_ + hf2;                                      \
            const half8v kf_ = *(const half8v*)&Ks[KR][row_ * 64 + 8 * (cb_ ^ (row_ & 7))]; \
            SN[jb_] = __builtin_amdgcn_mfma_f32_32x32x16_f16(kf_, qf[kk_], SN[jb_], 0, 0, 0); \
        } } while (0)

// exp2(SC) -> pk (permuted-k A-frags), lsum; then PV from V regs into accO
#define SOFTMAX_PV(SC, VR) do {                                                 \
    unsigned pk_[2][4][2];                                                      \
    _Pragma("unroll")                                                           \
    for (int jb_ = 0; jb_ < 2; ++jb_)                                           \
        _Pragma("unroll")                                                       \
        for (int g_ = 0; g_ < 4; ++g_) {                                        \
            const float p0_ = fast_exp2(SC[jb_][4 * g_ + 0]);                   \
            const float p1_ = fast_exp2(SC[jb_][4 * g_ + 1]);                   \
            const float p2_ = fast_exp2(SC[jb_][4 * g_ + 2]);                   \
            const float p3_ = fast_exp2(SC[jb_][4 * g_ + 3]);                   \
            lsum += (p0_ + p1_) + (p2_ + p3_);                                  \
            pk_[jb_][g_][0] = pack_bf16_trunc(p0_, p1_);                        \
            pk_[jb_][g_][1] = pack_bf16_trunc(p2_, p3_);                        \
        }                                                                       \
    __builtin_amdgcn_s_setprio(1);                                              \
    _Pragma("unroll")                                                           \
    for (int jc_ = 0; jc_ < 4; ++jc_) {                                         \
        const int jb_ = jc_ >> 1, gg_ = (jc_ & 1) * 2;                          \
        const uint4 uu_ = {pk_[jb_][gg_][0], pk_[jb_][gg_][1],                  \
                           pk_[jb_][gg_ + 1][0], pk_[jb_][gg_ + 1][1]};         \
        const short8v pa_ = __builtin_bit_cast(short8v, uu_);                   \
        _Pragma("unroll")                                                       \
        for (int db_ = 0; db_ < 2; ++db_)                                       \
            accO[db_] = __builtin_amdgcn_mfma_f32_32x32x16_bf16(pa_, VR[jc_][db_], accO[db_], 0, 0, 0); \
    }                                                                           \
    __builtin_amdgcn_s_setprio(0);                                              \
} while (0)

    // prologue: stage K(0)->Ks[0], K(1)->Ks[1]
    STAGE_K(0, 0);
    STAGE_K(1, 1);

    // Q B-frags: direct f16 load (pre-scaled by log2e in gemm_qkv);
    // lane holds Q[q = q0+wv*32+lq][d = kk*16 + hf2*8 + i]
    half8v qf[4];
    {
        const int qrow = q0 + wv * 32 + lq;
#pragma unroll
        for (int kk = 0; kk < 4; ++kk)
            qf[kk] = *(const half8v*)&qfp[(size_t)qrow * 64 + kk * 16 + hf2 * 8];
    }

    float16v accO[2];
#pragma unroll
    for (int db = 0; db < 2; ++db)
#pragma unroll
        for (int r = 0; r < 16; ++r) accO[db][r] = 0.f;
    float lsum = 0.f;

    float16v sA[2], sB[2];

    __syncthreads();            // K(0),K(1) DMA complete
    QK_STEP(sA, 0);             // QK(0) from Ks[0]
    __syncthreads();            // all waves done reading Ks[0] (no DMA pending)

    // Steady state, phases jt and jt+1 per loop iter:
    //  even phase jt:  LOADV(jt) [global, lands under QK+exp2];
    //                  stage K(jt+2)->Ks[0]; QK(jt+1)<-Ks[1];
    //                  exp2(jt)+PV(jt) from V regs
    //  odd phase jt+1: LOADV(jt+1); stage K(jt+3)->Ks[1]; QK(jt+2)<-Ks[0];
    //                  exp2(jt+1)+PV(jt+1)
    for (int jt = 0; jt < 32; jt += 2) {
        short8v vrA[4][2], vrB[4][2];
        // ---- even phase (jt) ----
        LOADV(vrA, jt);                        // V(jt) loads in flight
        if (jt + 2 < 32) STAGE_K(jt + 2, 0);
        QK_STEP(sB, 1);                        // QK(jt+1)
        SOFTMAX_PV(sA, vrA);                   // exp2(jt) + PV(jt)
        __syncthreads();
        // ---- odd phase (jt+1) ----
        LOADV(vrB, jt + 1);                    // V(jt+1) loads in flight
        if (jt + 3 < 32) STAGE_K(jt + 3, 1);
        if (jt + 2 < 32) QK_STEP(sA, 0);       // QK(jt+2)
        SOFTMAX_PV(sB, vrB);                   // exp2(jt+1) + PV(jt+1)
        __syncthreads();
    }

#undef STAGE_K
#undef LOADV
#undef QK_STEP
#undef SOFTMAX_PV

    // lane holds l-partial for q=lq over its half of j; combine halves
    const float ls = lsum + __shfl_xor(lsum, 32);
    const float invl = 1.f / ls;

    // epilogue: accO[db][4g+r] = O[q_local=r+8g+4*hf2][d=db*32+lq]
    const int b = bh >> 3, hh = bh & 7;
#pragma unroll
    for (int g = 0; g < 4; ++g)
#pragma unroll
        for (int r = 0; r < 4; ++r) {
            const int qrow = r + 8 * g + 4 * hf2;
            const float inv = __shfl(invl, qrow);   // lane qrow holds q=qrow
            const int q = q0 + wv * 32 + qrow;
#pragma unroll
            for (int db = 0; db < 2; ++db)
                OB[((size_t)(b * 2048 + q)) * 512 + hh * 64 + db * 32 + lq] =
                    f2bf(accO[db][4 * g + r] * inv);
        }
}

// ---------------------------------------------------------------------------
// GEMM2 (out projection): 128x64 tile, dbuf + prefetch, + XCD swizzle.
// ---------------------------------------------------------------------------
__global__ __launch_bounds__(256) void gemm_out(const unsigned short* __restrict__ OB,
                                                const unsigned short* __restrict__ Wob,
                                                float* __restrict__ out) {
    __shared__ unsigned short Asm[2][128 * 64];
    __shared__ unsigned short Bsm[2][64 * 64];
    const int t = threadIdx.x, wv = t >> 6, lane = t & 63;
    const int fm = lane & 15, fq = lane >> 4;
    // XCD swizzle: 512 blocks; each XCD owns 8 m-rows (A-panel L2-hot)
    const int bid0 = blockIdx.x + 8 * blockIdx.y;
    const int xcd = bid0 & 7, ii = bid0 >> 3;    // ii in 0..63
    const int e0 = (ii % 8) * 64;
    const int m0 = ((ii / 8) * 8 + xcd) * 128;
    const int wrow = (wv & 1) * 64, wcol = (wv >> 1) * 32;

    const int srow = t >> 3;
    const int skb0 = t & 7;

    float4v acc[4][2];
#pragma unroll
    for (int i = 0; i < 4; ++i)
#pragma unroll
        for (int j = 0; j < 2; ++j) acc[i][j] = (float4v){0.f, 0.f, 0.f, 0.f};

    // prologue: stage k0=0
#pragma unroll
    for (int i = 0; i < 4; ++i) {
        const int row = srow + 32 * i;
        const int kb = skb0 ^ (row & 7);
        gload_lds16(OB + (size_t)(m0 + row) * 512 + kb * 8,
                    &Asm[0][(wv * 64 + 256 * i) * 8]);
    }
#pragma unroll
    for (int i = 0; i < 2; ++i) {
        const int row = srow + 32 * i;
        const int kb = skb0 ^ (row & 7);
        gload_lds16(Wob + (size_t)(e0 + row) * 512 + kb * 8,
                    &Bsm[0][(wv * 64 + 256 * i) * 8]);
    }

    for (int kk = 0; kk < 8; ++kk) {
        __syncthreads();
        if (kk + 1 < 8) {
            const int k0n = (kk + 1) * 64, nbuf = (kk + 1) & 1;
#pragma unroll
            for (int i = 0; i < 4; ++i) {
                const int row = srow + 32 * i;
                const int kb = skb0 ^ (row & 7);
                gload_lds16(OB + (size_t)(m0 + row) * 512 + k0n + kb * 8,
                            &Asm[nbuf][(wv * 64 + 256 * i) * 8]);
            }
#pragma unroll
            for (int i = 0; i < 2; ++i) {
                const int row = srow + 32 * i;
                const int kb = skb0 ^ (row & 7);
                gload_lds16(Wob + (size_t)(e0 + row) * 512 + k0n + kb * 8,
                            &Bsm[nbuf][(wv * 64 + 256 * i) * 8]);
            }
        }
        const int buf = kk & 1;
#pragma unroll
        for (int ks = 0; ks < 2; ++ks) {
            short8v af[4], bf[2];
#pragma unroll
            for (int mt = 0; mt < 4; ++mt) {
                const int row = wrow + mt * 16 + fm;
                af[mt] = *(const short8v*)&Asm[buf][row * 64 + 8 * ((4 * ks + fq) ^ (row & 7))];
            }
#pragma unroll
            for (int nt = 0; nt < 2; ++nt) {
                const int row = wcol + nt * 16 + fm;
                bf[nt] = *(const short8v*)&Bsm[buf][row * 64 + 8 * ((4 * ks + fq) ^ (row & 7))];
            }
#pragma unroll
            for (int mt = 0; mt < 4; ++mt)
#pragma unroll
                for (int nt = 0; nt < 2; ++nt)
                    acc[mt][nt] = __builtin_amdgcn_mfma_f32_16x16x32_bf16(af[mt], bf[nt], acc[mt][nt], 0, 0, 0);
        }
    }
#pragma unroll
    for (int mt = 0; mt < 4; ++mt)
#pragma unroll
        for (int nt = 0; nt < 2; ++nt)
#pragma unroll
            for (int r = 0; r < 4; ++r) {
                const int m = m0 + wrow + mt * 16 + 4 * fq + r;
                const int e = e0 + wcol + nt * 16 + fm;
                out[(size_t)m * 512 + e] = acc[mt][nt][r];
            }
}

// ---------------------------------------------------------------------------
extern "C" void kernel_launch(void* const* d_in, const int* in_sizes, int n_in,
                              void* d_out, int out_size, void* d_ws, size_t ws_size,
                              hipStream_t stream) {
    const float* x     = (const float*)d_in[0];   // [B,S,D]
    const float* w_qkv = (const float*)d_in[1];   // [3D, D]
    const float* w_out = (const float*)d_in[2];   // [D, D]
    float* out = (float*)d_out;                   // [B,S,D]

    // workspace carve-up (bytes): total ~45 MB
    char* p = (char*)d_ws;
    unsigned short* Xp  = (unsigned short*)p;  p += (size_t)M_ * 1024 * 2;      // 16.8 MB
    unsigned short* Wh  = (unsigned short*)p;  p += (size_t)1536 * 512 * 2;     // 1.6 MB
    unsigned short* Wlq = (unsigned short*)p;  p += (size_t)512 * 512 * 2;      // 0.5 MB
    unsigned short* Wob = (unsigned short*)p;  p += (size_t)512 * 512 * 2;      // 0.5 MB
    unsigned short* Qf  = (unsigned short*)p;  p += (size_t)32 * S_ * 64 * 2;   // 8.4 MB (f16, x log2e)
    unsigned short* KH  = (unsigned short*)p;  p += (size_t)32 * S_ * 64 * 2;   // 8.4 MB (f16)
    unsigned short* VT  = (unsigned short*)p;  p += (size_t)32 * 64 * S_ * 2;   // 8.4 MB (bf16, j-permuted)
    unsigned short* OB  = Xp;  // Xp dead after gemm_qkv; reuse for attention output

    prepass<<<2560, 256, 0, stream>>>(x, w_qkv, w_out, Xp, Wh, Wlq, Wob);
    gemm_qkv<<<dim3(12, 64), 256, 0, stream>>>(Xp, Wh, Wlq, Qf, KH, VT);
    attn<<<dim3(16, 32), 256, 0, stream>>>(Qf, KH, VT, OB);
    gemm_out<<<dim3(8, 64), 256, 0, stream>>>(OB, Wob, out);
}

// Round 14
// 140.864 us; speedup vs baseline: 1.3153x; 1.3153x over previous
//
#include <hip/hip_runtime.h>
#include <hip/hip_bf16.h>

// Problem dims (fixed by the reference)
constexpr int B_  = 4;
constexpr int S_  = 2048;
constexpr int D_  = 512;
constexpr int H_  = 8;
constexpr int HD_ = 64;
constexpr int M_  = B_ * S_;   // 8192

constexpr float LOG2E = 1.4426950408889634f;

typedef __attribute__((ext_vector_type(8))) short short8v;            // 8 bf16 (4 VGPR) MFMA operand
typedef __attribute__((ext_vector_type(8))) _Float16 half8v;          // 8 f16 (4 VGPR) MFMA operand
typedef __attribute__((ext_vector_type(8))) unsigned short ushort8v;  // 16B staging chunk
typedef __attribute__((ext_vector_type(4))) float float4v;            // 16x16 MFMA C/D
typedef __attribute__((ext_vector_type(16))) float float16v;          // 32x32 MFMA C/D

__device__ __forceinline__ unsigned short f2bf(float x) {  // RNE fp32->bf16
    unsigned u = __builtin_bit_cast(unsigned, x);
    u += 0x7fffu + ((u >> 16) & 1u);
    return (unsigned short)(u >> 16);
}
__device__ __forceinline__ float bf2f(unsigned short h) {
    return __builtin_bit_cast(float, ((unsigned)h) << 16);
}
__device__ __forceinline__ unsigned short f2h(float x) {   // RNE fp32->fp16 bits
    return __builtin_bit_cast(unsigned short, (_Float16)x);
}
__device__ __forceinline__ float fast_exp2(float x) {
#if __has_builtin(__builtin_amdgcn_exp2f)
    return __builtin_amdgcn_exp2f(x);
#else
    return exp2f(x);
#endif
}
// pack two f32 as [trunc-bf16(lo) | trunc-bf16(hi)<<16]  (1 v_perm)
__device__ __forceinline__ unsigned pack_bf16_trunc(float lo, float hi) {
    const unsigned ulo = __builtin_bit_cast(unsigned, lo);
    const unsigned uhi = __builtin_bit_cast(unsigned, hi);
#if __has_builtin(__builtin_amdgcn_perm)
    return __builtin_amdgcn_perm(uhi, ulo, 0x07060302u);
#else
    return (uhi & 0xffff0000u) | (ulo >> 16);
#endif
}
// async global->LDS, 16B per lane; lds dest = wave-uniform base + lane*16
__device__ __forceinline__ void gload_lds16(const void* g, void* lds) {
    __builtin_amdgcn_global_load_lds((const __attribute__((address_space(1))) unsigned*)g,
                                     (__attribute__((address_space(3))) unsigned*)lds, 16, 0, 0);
}

// ---------------------------------------------------------------------------
// Prepass v14: single-precision-tier operands.
//   Xf  [8192][512] f16(x);  Wf [1536][512] f16(w_qkv);  Wob bf16(w_out).
// Rationale (R12): Q is stored f16 anyway (2^-11 floor) and K was computed
// from hi-bf16-only operands (2^-9 -- the worst error source, yet passing).
// f16 single-pass makes K/V MORE accurate, halves X bytes, deletes Wlq, and
// cuts gemm_qkv's q-slice from 24 to 8 k-iters.
// ---------------------------------------------------------------------------
__global__ __launch_bounds__(256) void prepass(const float* __restrict__ x,
                                               const float* __restrict__ wqkv,
                                               const float* __restrict__ wout,
                                               unsigned short* __restrict__ Xf,
                                               unsigned short* __restrict__ Wf,
                                               unsigned short* __restrict__ Wob) {
    const int bid = blockIdx.x, t = threadIdx.x;
    if (bid < 2048) {                      // x -> f16
        const int flat = bid * 256 + t;
        const int m = flat >> 6, c = (flat & 63) * 8;
        const float4 a = *(const float4*)&x[(size_t)m * 512 + c];
        const float4 b = *(const float4*)&x[(size_t)m * 512 + c + 4];
        const float v[8] = {a.x, a.y, a.z, a.w, b.x, b.y, b.z, b.w};
        ushort8v o;
#pragma unroll
        for (int i = 0; i < 8; ++i) o[i] = f2h(v[i]);
        *(ushort8v*)&Xf[(size_t)m * 512 + c] = o;
    } else if (bid < 2048 + 384) {         // w_qkv -> f16
        const int flat = (bid - 2048) * 256 + t;
        const int e = flat >> 6, c = (flat & 63) * 8;
        const float4 a = *(const float4*)&wqkv[(size_t)e * 512 + c];
        const float4 b = *(const float4*)&wqkv[(size_t)e * 512 + c + 4];
        const float v[8] = {a.x, a.y, a.z, a.w, b.x, b.y, b.z, b.w};
        ushort8v o;
#pragma unroll
        for (int i = 0; i < 8; ++i) o[i] = f2h(v[i]);
        *(ushort8v*)&Wf[(size_t)e * 512 + c] = o;
    } else {                               // w_out -> bf16
        const int flat = (bid - 2432) * 256 + t;
        const int e = flat >> 6, c = (flat & 63) * 8;
        const float4 a = *(const float4*)&wout[(size_t)e * 512 + c];
        const float4 b = *(const float4*)&wout[(size_t)e * 512 + c + 4];
        const float v[8] = {a.x, a.y, a.z, a.w, b.x, b.y, b.z, b.w};
        ushort8v o;
#pragma unroll
        for (int i = 0; i < 8; ++i) o[i] = f2bf(v[i]);
        *(ushort8v*)&Wob[(size_t)e * 512 + c] = o;
    }
}

// ---------------------------------------------------------------------------
// GEMM1 (QKV projection) v14: f16 single-pass, 128x128 tiles, BK=64, 8 iters
// for ALL slices (q-slice was 24 with the hi/lo scheme), dbuf+prefetch, XCD
// swizzle. Slices: x>>2 = 0:q 1:k 2:v; e0=(x&3)*128. Grid (12,64).
// Q stored f16 pre-scaled by log2e; K f16; V bf16 j-permuted (bits 2<->3).
// ---------------------------------------------------------------------------
__global__ __launch_bounds__(256, 2) void gemm_qkv(const unsigned short* __restrict__ Xf,
                                                   const unsigned short* __restrict__ Wf,
                                                   unsigned short* __restrict__ Qf,
                                                   unsigned short* __restrict__ KH,
                                                   unsigned short* __restrict__ VT) {
    __shared__ unsigned short Asm[2][128 * 64];   // 32 KB (f16 bits)
    __shared__ unsigned short Bsm[2][128 * 64];   // 32 KB
    const int t = threadIdx.x, wv = t >> 6, lane = t & 63;
    const int fm = lane & 15, fq = lane >> 4;
    const int bid0 = blockIdx.x + 12 * blockIdx.y;
    const int xcd = bid0 & 7, ii = bid0 >> 3;       // ii in 0..95
    const int x  = ii % 12;
    const int m0 = ((ii / 12) * 8 + xcd) * 128;
    const int slice = x >> 2;            // 0=q 1=k 2=v
    const int e0 = (x & 3) * 128;        // within the 512-wide segment
    const bool vblk = (slice == 2);
    const int wrow = (wv >> 1) * 64, wcol = (wv & 1) * 64;

    const unsigned short* Bbase = Wf + (size_t)(e0 + slice * 512) * 512;

    const int srow = t >> 3;     // 0..31; +32*i extends
    const int skb0 = t & 7;

    float4v acc[4][4];
#pragma unroll
    for (int i = 0; i < 4; ++i)
#pragma unroll
        for (int j = 0; j < 4; ++j) acc[i][j] = (float4v){0.f, 0.f, 0.f, 0.f};

    // prologue: stage tile kk=0 into buf 0
#pragma unroll
    for (int i = 0; i < 4; ++i) {
        const int row = srow + 32 * i;
        const int kb = skb0 ^ (row & 7);
        gload_lds16(Xf + (size_t)(m0 + row) * 512 + kb * 8,
                    &Asm[0][(wv * 64 + 256 * i) * 8]);
        gload_lds16(Bbase + (size_t)row * 512 + kb * 8,
                    &Bsm[0][(wv * 64 + 256 * i) * 8]);
    }

    for (int kk = 0; kk < 8; ++kk) {
        __syncthreads();   // tile kk DMA complete; buf[(kk+1)&1] free

        if (kk + 1 < 8) {          // prefetch tile kk+1 (overlaps compute of kk)
            const int k0n = (kk + 1) * 64;
            const int nbuf = (kk + 1) & 1;
#pragma unroll
            for (int i = 0; i < 4; ++i) {
                const int row = srow + 32 * i;
                const int kb = skb0 ^ (row & 7);
                gload_lds16(Xf + (size_t)(m0 + row) * 512 + k0n + kb * 8,
                            &Asm[nbuf][(wv * 64 + 256 * i) * 8]);
                gload_lds16(Bbase + (size_t)row * 512 + k0n + kb * 8,
                            &Bsm[nbuf][(wv * 64 + 256 * i) * 8]);
            }
        }

        const int buf = kk & 1;
#pragma unroll
        for (int ks = 0; ks < 2; ++ks) {
            half8v af[4], bf[4];
#pragma unroll
            for (int mt = 0; mt < 4; ++mt) {
                const int row = wrow + mt * 16 + fm;
                af[mt] = *(const half8v*)&Asm[buf][row * 64 + 8 * ((4 * ks + fq) ^ (row & 7))];
            }
#pragma unroll
            for (int nt = 0; nt < 4; ++nt) {
                const int row = wcol + nt * 16 + fm;
                bf[nt] = *(const half8v*)&Bsm[buf][row * 64 + 8 * ((4 * ks + fq) ^ (row & 7))];
            }
            if (vblk) {
#pragma unroll
                for (int mt = 0; mt < 4; ++mt)
#pragma unroll
                    for (int nt = 0; nt < 4; ++nt)
                        acc[mt][nt] = __builtin_amdgcn_mfma_f32_16x16x32_f16(bf[nt], af[mt], acc[mt][nt], 0, 0, 0);
            } else {
#pragma unroll
                for (int mt = 0; mt < 4; ++mt)
#pragma unroll
                    for (int nt = 0; nt < 4; ++nt)
                        acc[mt][nt] = __builtin_amdgcn_mfma_f32_16x16x32_f16(af[mt], bf[nt], acc[mt][nt], 0, 0, 0);
            }
        }
    }

    if (!vblk) {
        // q: f16 store pre-scaled by log2e; k: f16 store
        unsigned short* __restrict__ dst = (slice == 0) ? Qf : KH;
        const float sc = (slice == 0) ? LOG2E : 1.0f;
#pragma unroll
        for (int mt = 0; mt < 4; ++mt)
#pragma unroll
            for (int nt = 0; nt < 4; ++nt) {
                const int e = e0 + wcol + nt * 16 + fm;
                const int h = e >> 6, hd = e & 63;
#pragma unroll
                for (int r = 0; r < 4; ++r) {
                    const int m = m0 + wrow + mt * 16 + 4 * fq + r;
                    const int b = m >> 11, s = m & 2047;
                    dst[((size_t)(b * 8 + h) * 2048 + s) * 64 + hd] =
                        f2h(acc[mt][nt][r] * sc);
                }
            }
    } else {
        // v: acc rows = e (4fq+r), cols = m (fm);
        // store at j-permuted column s2 (swap bits 2<->3 within 16-group)
#pragma unroll
        for (int nt = 0; nt < 4; ++nt)
#pragma unroll
            for (int r = 0; r < 4; ++r) {
                const int e = e0 + wcol + nt * 16 + 4 * fq + r;
                const int h = e >> 6, hd = e & 63;
#pragma unroll
                for (int mt = 0; mt < 4; ++mt) {
                    const int m = m0 + wrow + mt * 16 + fm;
                    const int b = m >> 11, s = m & 2047;
                    const int s2 = (s & ~12) | ((s & 4) << 1) | ((s & 8) >> 1);
                    VT[((size_t)(b * 8 + h) * 64 + hd) * 2048 + s2] = f2bf(acc[mt][nt][r]);
                }
            }
    }
}

// ---------------------------------------------------------------------------
// MFMA flash attention (v7, best measured 46.2us) -- reinstated VERBATIM.
// R12 post-mortem: v13's direct-from-L2 V reads quadrupled L2-side traffic
// (each wave fetches separately vs one DMA broadcast serving 4 waves) and
// coupled V waits with K-DMA vmcnt -> 46->72us regression. The v7 LDS
// broadcast + one-phase pipeline is the empirical plateau for this geometry.
// ---------------------------------------------------------------------------
__global__ __launch_bounds__(256, 2) void attn(const unsigned short* __restrict__ Qfp,
                                               const unsigned short* __restrict__ KHp,
                                               const unsigned short* __restrict__ VTp,
                                               unsigned short* __restrict__ OB) {
    __shared__ unsigned short Ks[2][64 * 64];    // 16 KB, f16 K tiles [j][d], XOR-swizzled
    __shared__ unsigned short Vs[2][64 * 64];    // 16 KB, bf16 V^T tiles [d][j-perm], XOR-swizzled
    const int t = threadIdx.x, wv = t >> 6, lane = t & 63;
    const int lq = lane & 31;     // q (and d/j) index within 32
    const int hf2 = lane >> 5;    // half-wave
    // XCD swizzle: 512 blocks, xcd = bid%8; each XCD owns 4 bh (K/V L2-hot)
    const int bid0 = blockIdx.x + 16 * blockIdx.y;
    const int xcd = bid0 & 7, ii = bid0 >> 3;    // ii in 0..63
    const int bh = (ii & 3) * 8 + xcd;
    const int q0 = (ii >> 2) * 128;

    const unsigned short* qfp = Qfp + (size_t)bh * S_ * 64;
    const unsigned short* kh  = KHp + (size_t)bh * S_ * 64;
    const unsigned short* vt  = VTp + (size_t)bh * 64 * S_;

    const int srow = t >> 3;     // 0..31
    const int skb0 = t & 7;

// stage K tile N (64 rows of 64 f16) into Ks[B]; wave wv covers rows 8wv..+7, +32
#define STAGE_K(N, B) do {                                                      \
    _Pragma("unroll")                                                           \
    for (int i_ = 0; i_ < 2; ++i_) {                                            \
        const int row_ = srow + 32 * i_;                                        \
        const int kb_ = skb0 ^ (row_ & 7);                                      \
        gload_lds16(kh + (size_t)((N) * 64 + row_) * 64 + kb_ * 8,              \
                    &Ks[B][(wv * 64 + 256 * i_) * 8]);                          \
    } } while (0)

// stage V^T tile N (64 d-rows x 64 j) into Vs[B]
#define STAGE_V(N, B) do {                                                      \
    _Pragma("unroll")                                                           \
    for (int i_ = 0; i_ < 2; ++i_) {                                            \
        const int row_ = srow + 32 * i_;                                        \
        const int kb_ = skb0 ^ (row_ & 7);                                      \
        gload_lds16(vt + (size_t)row_ * S_ + (N) * 64 + kb_ * 8,                \
                    &Vs[B][(wv * 64 + 256 * i_) * 8]);                          \
    } } while (0)

// QK^T for one tile from Ks[KR] into SN (zeroed here):
// lane (lq,hf2) reg 4g+r of SN[jb] = S[q=lq][j = jb*32 + r + 8g + 4*hf2]
#define QK_STEP(SN, KR) do {                                                    \
    _Pragma("unroll")                                                           \
    for (int jb_ = 0; jb_ < 2; ++jb_)                                           \
        _Pragma("unroll")                                                       \
        for (int r_ = 0; r_ < 16; ++r_) SN[jb_][r_] = 0.f;                      \
    _Pragma("unroll")                                                           \
    for (int kk_ = 0; kk_ < 4; ++kk_)                                           \
        _Pragma("unroll")                                                       \
        for (int jb_ = 0; jb_ < 2; ++jb_) {                                     \
            const int row_ = jb_ * 32 + lq;                                     \
            const int cb_ = 2 * kk_ + hf2;                                      \
            const half8v kf_ = *(const half8v*)&Ks[KR][row_ * 64 + 8 * (cb_ ^ (row_ & 7))]; \
            SN[jb_] = __builtin_amdgcn_mfma_f32_32x32x16_f16(kf_, qf[kk_], SN[jb_], 0, 0, 0); \
        } } while (0)

// exp2(SC) -> pk (permuted-k A-frags), lsum; then PV from Vs[VR] into accO
#define SOFTMAX_PV(SC, VR) do {                                                 \
    unsigned pk_[2][4][2];                                                      \
    _Pragma("unroll")                                                           \
    for (int jb_ = 0; jb_ < 2; ++jb_)                                           \
        _Pragma("unroll")                                                       \
        for (int g_ = 0; g_ < 4; ++g_) {                                        \
            const float p0_ = fast_exp2(SC[jb_][4 * g_ + 0]);                   \
            const float p1_ = fast_exp2(SC[jb_][4 * g_ + 1]);                   \
            const float p2_ = fast_exp2(SC[jb_][4 * g_ + 2]);                   \
            const float p3_ = fast_exp2(SC[jb_][4 * g_ + 3]);                   \
            lsum += (p0_ + p1_) + (p2_ + p3_);                                  \
            pk_[jb_][g_][0] = pack_bf16_trunc(p0_, p1_);                        \
            pk_[jb_][g_][1] = pack_bf16_trunc(p2_, p3_);                        \
        }                                                                       \
    __builtin_amdgcn_s_setprio(1);                                              \
    _Pragma("unroll")                                                           \
    for (int jc_ = 0; jc_ < 4; ++jc_) {                                         \
        const int jb_ = jc_ >> 1, gg_ = (jc_ & 1) * 2;                          \
        const uint4 uu_ = {pk_[jb_][gg_][0], pk_[jb_][gg_][1],                  \
                           pk_[jb_][gg_ + 1][0], pk_[jb_][gg_ + 1][1]};         \
        const short8v pa_ = __builtin_bit_cast(short8v, uu_);                   \
        _Pragma("unroll")                                                       \
        for (int db_ = 0; db_ < 2; ++db_) {                                     \
            const int vrow_ = db_ * 32 + lq;                                    \
            const int cb_ = 2 * jc_ + hf2;                                      \
            const short8v vf_ = *(const short8v*)&Vs[VR][vrow_ * 64 + 8 * (cb_ ^ (vrow_ & 7))]; \
            accO[db_] = __builtin_amdgcn_mfma_f32_32x32x16_bf16(pa_, vf_, accO[db_], 0, 0, 0);  \
        }                                                                       \
    }                                                                           \
    __builtin_amdgcn_s_setprio(0);                                              \
} while (0)

    // prologue: stage K(0)->Ks[0], V(0)->Vs[0], K(1)->Ks[1]
    STAGE_K(0, 0);
    STAGE_V(0, 0);
    STAGE_K(1, 1);

    // Q B-frags: direct f16 load (pre-scaled by log2e in gemm_qkv);
    // lane holds Q[q = q0+wv*32+lq][d = kk*16 + hf2*8 + i]
    half8v qf[4];
    {
        const int qrow = q0 + wv * 32 + lq;
#pragma unroll
        for (int kk = 0; kk < 4; ++kk)
            qf[kk] = *(const half8v*)&qfp[(size_t)qrow * 64 + kk * 16 + hf2 * 8];
    }

    float16v accO[2];
#pragma unroll
    for (int db = 0; db < 2; ++db)
#pragma unroll
        for (int r = 0; r < 16; ++r) accO[db][r] = 0.f;
    float lsum = 0.f;

    float16v sA[2], sB[2];

    __syncthreads();            // K(0),V(0),K(1) DMA complete
    QK_STEP(sA, 0);             // QK(0) from Ks[0]
    __syncthreads();            // all waves done reading Ks[0] (no DMA pending)

    // Steady state, phases jt and jt+1 per loop iter:
    //  even phase jt:   QK(jt+1)<-Ks[1], exp2+PV(jt)<-Vs[0];
    //                   stage K(jt+2)->Ks[0], V(jt+1)->Vs[1]
    //  odd phase jt+1:  QK(jt+2)<-Ks[0], exp2+PV(jt+1)<-Vs[1];
    //                   stage K(jt+3)->Ks[1], V(jt+2)->Vs[0]
    for (int jt = 0; jt < 32; jt += 2) {
        // ---- even phase (jt) ----
        if (jt + 2 < 32) STAGE_K(jt + 2, 0);
        STAGE_V(jt + 1, 1);                    // jt+1 <= 31 always here
        QK_STEP(sB, 1);                        // QK(jt+1)
        SOFTMAX_PV(sA, 0);                     // exp2(jt) + PV(jt)
        __syncthreads();
        // ---- odd phase (jt+1) ----
        if (jt + 3 < 32) STAGE_K(jt + 3, 1);
        if (jt + 2 < 32) {
            STAGE_V(jt + 2, 0);
            QK_STEP(sA, 0);                    // QK(jt+2)
        }
        SOFTMAX_PV(sB, 1);                     // exp2(jt+1) + PV(jt+1)
        __syncthreads();
    }

#undef STAGE_K
#undef STAGE_V
#undef QK_STEP
#undef SOFTMAX_PV

    // lane holds l-partial for q=lq over its half of j; combine halves
    const float ls = lsum + __shfl_xor(lsum, 32);
    const float invl = 1.f / ls;

    // epilogue: accO[db][4g+r] = O[q_local=r+8g+4*hf2][d=db*32+lq]
    const int b = bh >> 3, hh = bh & 7;
#pragma unroll
    for (int g = 0; g < 4; ++g)
#pragma unroll
        for (int r = 0; r < 4; ++r) {
            const int qrow = r + 8 * g + 4 * hf2;
            const float inv = __shfl(invl, qrow);   // lane qrow holds q=qrow
            const int q = q0 + wv * 32 + qrow;
#pragma unroll
            for (int db = 0; db < 2; ++db)
                OB[((size_t)(b * 2048 + q)) * 512 + hh * 64 + db * 32 + lq] =
                    f2bf(accO[db][4 * g + r] * inv);
        }
}

// ---------------------------------------------------------------------------
// GEMM2 (out projection) v14: 128x128 tile (same proven step as gemm_qkv),
// BK=64, dbuf + prefetch, bijective XCD swizzle. Grid (4,64) = 256 blocks.
// ---------------------------------------------------------------------------
__global__ __launch_bounds__(256, 2) void gemm_out(const unsigned short* __restrict__ OB,
                                                   const unsigned short* __restrict__ Wob,
                                                   float* __restrict__ out) {
    __shared__ unsigned short Asm[2][128 * 64];   // 32 KB
    __shared__ unsigned short Bsm[2][128 * 64];   // 32 KB
    const int t = threadIdx.x, wv = t >> 6, lane = t & 63;
    const int fm = lane & 15, fq = lane >> 4;
    const int bid0 = blockIdx.x + 4 * blockIdx.y;
    const int xcd = bid0 & 7, ii = bid0 >> 3;    // ii in 0..31
    const int e0 = (ii % 4) * 128;
    const int m0 = ((ii / 4) * 8 + xcd) * 128;
    const int wrow = (wv >> 1) * 64, wcol = (wv & 1) * 64;

    const int srow = t >> 3;
    const int skb0 = t & 7;

    float4v acc[4][4];
#pragma unroll
    for (int i = 0; i < 4; ++i)
#pragma unroll
        for (int j = 0; j < 4; ++j) acc[i][j] = (float4v){0.f, 0.f, 0.f, 0.f};

    // prologue: stage k0=0
#pragma unroll
    for (int i = 0; i < 4; ++i) {
        const int row = srow + 32 * i;
        const int kb = skb0 ^ (row & 7);
        gload_lds16(OB + (size_t)(m0 + row) * 512 + kb * 8,
                    &Asm[0][(wv * 64 + 256 * i) * 8]);
        gload_lds16(Wob + (size_t)(e0 + row) * 512 + kb * 8,
                    &Bsm[0][(wv * 64 + 256 * i) * 8]);
    }

    for (int kk = 0; kk < 8; ++kk) {
        __syncthreads();
        if (kk + 1 < 8) {
            const int k0n = (kk + 1) * 64, nbuf = (kk + 1) & 1;
#pragma unroll
            for (int i = 0; i < 4; ++i) {
                const int row = srow + 32 * i;
                const int kb = skb0 ^ (row & 7);
                gload_lds16(OB + (size_t)(m0 + row) * 512 + k0n + kb * 8,
                            &Asm[nbuf][(wv * 64 + 256 * i) * 8]);
                gload_lds16(Wob + (size_t)(e0 + row) * 512 + k0n + kb * 8,
                            &Bsm[nbuf][(wv * 64 + 256 * i) * 8]);
            }
        }
        const int buf = kk & 1;
#pragma unroll
        for (int ks = 0; ks < 2; ++ks) {
            short8v af[4], bf[4];
#pragma unroll
            for (int mt = 0; mt < 4; ++mt) {
                const int row = wrow + mt * 16 + fm;
                af[mt] = *(const short8v*)&Asm[buf][row * 64 + 8 * ((4 * ks + fq) ^ (row & 7))];
            }
#pragma unroll
            for (int nt = 0; nt < 4; ++nt) {
                const int row = wcol + nt * 16 + fm;
                bf[nt] = *(const short8v*)&Bsm[buf][row * 64 + 8 * ((4 * ks + fq) ^ (row & 7))];
            }
#pragma unroll
            for (int mt = 0; mt < 4; ++mt)
#pragma unroll
                for (int nt = 0; nt < 4; ++nt)
                    acc[mt][nt] = __builtin_amdgcn_mfma_f32_16x16x32_bf16(af[mt], bf[nt], acc[mt][nt], 0, 0, 0);
        }
    }
#pragma unroll
    for (int mt = 0; mt < 4; ++mt)
#pragma unroll
        for (int nt = 0; nt < 4; ++nt)
#pragma unroll
            for (int r = 0; r < 4; ++r) {
                const int m = m0 + wrow + mt * 16 + 4 * fq + r;
                const int e = e0 + wcol + nt * 16 + fm;
                out[(size_t)m * 512 + e] = acc[mt][nt][r];
            }
}

// ---------------------------------------------------------------------------
extern "C" void kernel_launch(void* const* d_in, const int* in_sizes, int n_in,
                              void* d_out, int out_size, void* d_ws, size_t ws_size,
                              hipStream_t stream) {
    const float* x     = (const float*)d_in[0];   // [B,S,D]
    const float* w_qkv = (const float*)d_in[1];   // [3D, D]
    const float* w_out = (const float*)d_in[2];   // [D, D]
    float* out = (float*)d_out;                   // [B,S,D]

    // workspace carve-up (bytes): total ~36 MB
    char* p = (char*)d_ws;
    unsigned short* Xf  = (unsigned short*)p;  p += (size_t)M_ * 512 * 2;       // 8.4 MB (f16)
    unsigned short* Wf  = (unsigned short*)p;  p += (size_t)1536 * 512 * 2;     // 1.6 MB (f16)
    unsigned short* Wob = (unsigned short*)p;  p += (size_t)512 * 512 * 2;      // 0.5 MB (bf16)
    unsigned short* Qf  = (unsigned short*)p;  p += (size_t)32 * S_ * 64 * 2;   // 8.4 MB (f16, x log2e)
    unsigned short* KH  = (unsigned short*)p;  p += (size_t)32 * S_ * 64 * 2;   // 8.4 MB (f16)
    unsigned short* VT  = (unsigned short*)p;  p += (size_t)32 * 64 * S_ * 2;   // 8.4 MB (bf16, j-permuted)
    unsigned short* OB  = Xf;  // Xf dead after gemm_qkv; reuse for attention output

    prepass<<<2560, 256, 0, stream>>>(x, w_qkv, w_out, Xf, Wf, Wob);
    gemm_qkv<<<dim3(12, 64), 256, 0, stream>>>(Xf, Wf, Qf, KH, VT);
    attn<<<dim3(16, 32), 256, 0, stream>>>(Qf, KH, VT, OB);
    gemm_out<<<dim3(4, 64), 256, 0, stream>>>(OB, Wob, out);
}

// Round 15
// 140.565 us; speedup vs baseline: 1.3181x; 1.0021x over previous
//
#include <hip/hip_runtime.h>
#include <hip/hip_bf16.h>

// Problem dims (fixed by the reference)
constexpr int B_  = 4;
constexpr int S_  = 2048;
constexpr int D_  = 512;
constexpr int H_  = 8;
constexpr int HD_ = 64;
constexpr int M_  = B_ * S_;   // 8192

constexpr float LOG2E = 1.4426950408889634f;

typedef __attribute__((ext_vector_type(8))) short short8v;            // 8 bf16 (4 VGPR) MFMA operand
typedef __attribute__((ext_vector_type(8))) _Float16 half8v;          // 8 f16 (4 VGPR) MFMA operand
typedef __attribute__((ext_vector_type(8))) unsigned short ushort8v;  // 16B staging chunk
typedef __attribute__((ext_vector_type(4))) float float4v;            // 16x16 MFMA C/D
typedef __attribute__((ext_vector_type(16))) float float16v;          // 32x32 MFMA C/D

__device__ __forceinline__ unsigned short f2bf(float x) {  // RNE fp32->bf16
    unsigned u = __builtin_bit_cast(unsigned, x);
    u += 0x7fffu + ((u >> 16) & 1u);
    return (unsigned short)(u >> 16);
}
__device__ __forceinline__ float bf2f(unsigned short h) {
    return __builtin_bit_cast(float, ((unsigned)h) << 16);
}
__device__ __forceinline__ unsigned short f2h(float x) {   // RNE fp32->fp16 bits
    return __builtin_bit_cast(unsigned short, (_Float16)x);
}
__device__ __forceinline__ float fast_exp2(float x) {
#if __has_builtin(__builtin_amdgcn_exp2f)
    return __builtin_amdgcn_exp2f(x);
#else
    return exp2f(x);
#endif
}
// pack two f32 as [trunc-bf16(lo) | trunc-bf16(hi)<<16]  (1 v_perm)
__device__ __forceinline__ unsigned pack_bf16_trunc(float lo, float hi) {
    const unsigned ulo = __builtin_bit_cast(unsigned, lo);
    const unsigned uhi = __builtin_bit_cast(unsigned, hi);
#if __has_builtin(__builtin_amdgcn_perm)
    return __builtin_amdgcn_perm(uhi, ulo, 0x07060302u);
#else
    return (uhi & 0xffff0000u) | (ulo >> 16);
#endif
}
// async global->LDS, 16B per lane; lds dest = wave-uniform base + lane*16
__device__ __forceinline__ void gload_lds16(const void* g, void* lds) {
    __builtin_amdgcn_global_load_lds((const __attribute__((address_space(1))) unsigned*)g,
                                     (__attribute__((address_space(3))) unsigned*)lds, 16, 0, 0);
}

// ---------------------------------------------------------------------------
// Prepass: single-precision-tier operands.
//   Xf  [8192][512] f16(x);  Wf [1536][512] f16(w_qkv);  Wob bf16(w_out).
// ---------------------------------------------------------------------------
__global__ __launch_bounds__(256) void prepass(const float* __restrict__ x,
                                               const float* __restrict__ wqkv,
                                               const float* __restrict__ wout,
                                               unsigned short* __restrict__ Xf,
                                               unsigned short* __restrict__ Wf,
                                               unsigned short* __restrict__ Wob) {
    const int bid = blockIdx.x, t = threadIdx.x;
    if (bid < 2048) {                      // x -> f16
        const int flat = bid * 256 + t;
        const int m = flat >> 6, c = (flat & 63) * 8;
        const float4 a = *(const float4*)&x[(size_t)m * 512 + c];
        const float4 b = *(const float4*)&x[(size_t)m * 512 + c + 4];
        const float v[8] = {a.x, a.y, a.z, a.w, b.x, b.y, b.z, b.w};
        ushort8v o;
#pragma unroll
        for (int i = 0; i < 8; ++i) o[i] = f2h(v[i]);
        *(ushort8v*)&Xf[(size_t)m * 512 + c] = o;
    } else if (bid < 2048 + 384) {         // w_qkv -> f16
        const int flat = (bid - 2048) * 256 + t;
        const int e = flat >> 6, c = (flat & 63) * 8;
        const float4 a = *(const float4*)&wqkv[(size_t)e * 512 + c];
        const float4 b = *(const float4*)&wqkv[(size_t)e * 512 + c + 4];
        const float v[8] = {a.x, a.y, a.z, a.w, b.x, b.y, b.z, b.w};
        ushort8v o;
#pragma unroll
        for (int i = 0; i < 8; ++i) o[i] = f2h(v[i]);
        *(ushort8v*)&Wf[(size_t)e * 512 + c] = o;
    } else {                               // w_out -> bf16
        const int flat = (bid - 2432) * 256 + t;
        const int e = flat >> 6, c = (flat & 63) * 8;
        const float4 a = *(const float4*)&wout[(size_t)e * 512 + c];
        const float4 b = *(const float4*)&wout[(size_t)e * 512 + c + 4];
        const float v[8] = {a.x, a.y, a.z, a.w, b.x, b.y, b.z, b.w};
        ushort8v o;
#pragma unroll
        for (int i = 0; i < 8; ++i) o[i] = f2bf(v[i]);
        *(ushort8v*)&Wob[(size_t)e * 512 + c] = o;
    }
}

// ---------------------------------------------------------------------------
// GEMM1 (QKV projection): f16 single-pass, 128x128 tiles, BK=64, 8 iters,
// dbuf+prefetch, XCD swizzle. Slices: x>>2 = 0:q 1:k 2:v; e0=(x&3)*128.
// Grid (12,64). Q stored f16 pre-scaled by log2e; K f16; V bf16 j-permuted.
// ---------------------------------------------------------------------------
__global__ __launch_bounds__(256, 2) void gemm_qkv(const unsigned short* __restrict__ Xf,
                                                   const unsigned short* __restrict__ Wf,
                                                   unsigned short* __restrict__ Qf,
                                                   unsigned short* __restrict__ KH,
                                                   unsigned short* __restrict__ VT) {
    __shared__ unsigned short Asm[2][128 * 64];   // 32 KB (f16 bits)
    __shared__ unsigned short Bsm[2][128 * 64];   // 32 KB
    const int t = threadIdx.x, wv = t >> 6, lane = t & 63;
    const int fm = lane & 15, fq = lane >> 4;
    const int bid0 = blockIdx.x + 12 * blockIdx.y;
    const int xcd = bid0 & 7, ii = bid0 >> 3;       // ii in 0..95
    const int x  = ii % 12;
    const int m0 = ((ii / 12) * 8 + xcd) * 128;
    const int slice = x >> 2;            // 0=q 1=k 2=v
    const int e0 = (x & 3) * 128;        // within the 512-wide segment
    const bool vblk = (slice == 2);
    const int wrow = (wv >> 1) * 64, wcol = (wv & 1) * 64;

    const unsigned short* Bbase = Wf + (size_t)(e0 + slice * 512) * 512;

    const int srow = t >> 3;     // 0..31; +32*i extends
    const int skb0 = t & 7;

    float4v acc[4][4];
#pragma unroll
    for (int i = 0; i < 4; ++i)
#pragma unroll
        for (int j = 0; j < 4; ++j) acc[i][j] = (float4v){0.f, 0.f, 0.f, 0.f};

    // prologue: stage tile kk=0 into buf 0
#pragma unroll
    for (int i = 0; i < 4; ++i) {
        const int row = srow + 32 * i;
        const int kb = skb0 ^ (row & 7);
        gload_lds16(Xf + (size_t)(m0 + row) * 512 + kb * 8,
                    &Asm[0][(wv * 64 + 256 * i) * 8]);
        gload_lds16(Bbase + (size_t)row * 512 + kb * 8,
                    &Bsm[0][(wv * 64 + 256 * i) * 8]);
    }

    for (int kk = 0; kk < 8; ++kk) {
        __syncthreads();   // tile kk DMA complete; buf[(kk+1)&1] free

        if (kk + 1 < 8) {          // prefetch tile kk+1 (overlaps compute of kk)
            const int k0n = (kk + 1) * 64;
            const int nbuf = (kk + 1) & 1;
#pragma unroll
            for (int i = 0; i < 4; ++i) {
                const int row = srow + 32 * i;
                const int kb = skb0 ^ (row & 7);
                gload_lds16(Xf + (size_t)(m0 + row) * 512 + k0n + kb * 8,
                            &Asm[nbuf][(wv * 64 + 256 * i) * 8]);
                gload_lds16(Bbase + (size_t)row * 512 + k0n + kb * 8,
                            &Bsm[nbuf][(wv * 64 + 256 * i) * 8]);
            }
        }

        const int buf = kk & 1;
#pragma unroll
        for (int ks = 0; ks < 2; ++ks) {
            half8v af[4], bf[4];
#pragma unroll
            for (int mt = 0; mt < 4; ++mt) {
                const int row = wrow + mt * 16 + fm;
                af[mt] = *(const half8v*)&Asm[buf][row * 64 + 8 * ((4 * ks + fq) ^ (row & 7))];
            }
#pragma unroll
            for (int nt = 0; nt < 4; ++nt) {
                const int row = wcol + nt * 16 + fm;
                bf[nt] = *(const half8v*)&Bsm[buf][row * 64 + 8 * ((4 * ks + fq) ^ (row & 7))];
            }
            if (vblk) {
#pragma unroll
                for (int mt = 0; mt < 4; ++mt)
#pragma unroll
                    for (int nt = 0; nt < 4; ++nt)
                        acc[mt][nt] = __builtin_amdgcn_mfma_f32_16x16x32_f16(bf[nt], af[mt], acc[mt][nt], 0, 0, 0);
            } else {
#pragma unroll
                for (int mt = 0; mt < 4; ++mt)
#pragma unroll
                    for (int nt = 0; nt < 4; ++nt)
                        acc[mt][nt] = __builtin_amdgcn_mfma_f32_16x16x32_f16(af[mt], bf[nt], acc[mt][nt], 0, 0, 0);
            }
        }
    }

    if (!vblk) {
        // q: f16 store pre-scaled by log2e; k: f16 store
        unsigned short* __restrict__ dst = (slice == 0) ? Qf : KH;
        const float sc = (slice == 0) ? LOG2E : 1.0f;
#pragma unroll
        for (int mt = 0; mt < 4; ++mt)
#pragma unroll
            for (int nt = 0; nt < 4; ++nt) {
                const int e = e0 + wcol + nt * 16 + fm;
                const int h = e >> 6, hd = e & 63;
#pragma unroll
                for (int r = 0; r < 4; ++r) {
                    const int m = m0 + wrow + mt * 16 + 4 * fq + r;
                    const int b = m >> 11, s = m & 2047;
                    dst[((size_t)(b * 8 + h) * 2048 + s) * 64 + hd] =
                        f2h(acc[mt][nt][r] * sc);
                }
            }
    } else {
        // v: acc rows = e (4fq+r), cols = m (fm);
        // store at j-permuted column s2 (swap bits 2<->3 within 16-group)
#pragma unroll
        for (int nt = 0; nt < 4; ++nt)
#pragma unroll
            for (int r = 0; r < 4; ++r) {
                const int e = e0 + wcol + nt * 16 + 4 * fq + r;
                const int h = e >> 6, hd = e & 63;
#pragma unroll
                for (int mt = 0; mt < 4; ++mt) {
                    const int m = m0 + wrow + mt * 16 + fm;
                    const int b = m >> 11, s = m & 2047;
                    const int s2 = (s & ~12) | ((s & 4) << 1) | ((s & 8) >> 1);
                    VT[((size_t)(b * 8 + h) * 64 + hd) * 2048 + s2] = f2bf(acc[mt][nt][r]);
                }
            }
    }
}

// ---------------------------------------------------------------------------
// MFMA flash attention v15: v7 pipeline, ONE 8-wave block per CU (BQ=256,
// 512 threads, grid 256 = 1 block/CU). Keeps 2 waves/SIMD (v8's failure was
// 1/SIMD -- not repeated) and per-wave work/registers identical to v7, but
// HALVES the DMA side of the LDS port: per CU-phase 192 KB (2 blocks each
// staging 32 KB + 4x16 KB reads) -> 160 KB (one 32 KB stage + 8x16 KB reads).
// Staging is one pass/tile: 512 thr x 16B = full 64x64 tile; wave wv's
// gload dest stays wave-uniform (&buf[wv*512], lane x16 covers rows
// 8wv..8wv+7); per-thread gloads/phase 4 -> 2 (shallower vmcnt drain).
// ---------------------------------------------------------------------------
__global__ __launch_bounds__(512, 1) void attn(const unsigned short* __restrict__ Qfp,
                                               const unsigned short* __restrict__ KHp,
                                               const unsigned short* __restrict__ VTp,
                                               unsigned short* __restrict__ OB) {
    __shared__ unsigned short Ks[2][64 * 64];    // 16 KB, f16 K tiles [j][d], XOR-swizzled
    __shared__ unsigned short Vs[2][64 * 64];    // 16 KB, bf16 V^T tiles [d][j-perm], XOR-swizzled
    const int t = threadIdx.x, wv = t >> 6, lane = t & 63;
    const int lq = lane & 31;     // q (and d/j) index within 32
    const int hf2 = lane >> 5;    // half-wave
    // XCD swizzle: 256 blocks, xcd = bid%8; each XCD owns 4 bh (K/V L2-hot)
    const int bid0 = blockIdx.x + 8 * blockIdx.y;
    const int xcd = bid0 & 7, ii = bid0 >> 3;    // ii in 0..31
    const int bh = (ii & 3) * 8 + xcd;
    const int q0 = (ii >> 2) * 256;

    const unsigned short* qfp = Qfp + (size_t)bh * S_ * 64;
    const unsigned short* kh  = KHp + (size_t)bh * S_ * 64;
    const unsigned short* vt  = VTp + (size_t)bh * 64 * S_;

    const int srow = t >> 3;     // 0..63 (512 threads cover the tile in one pass)
    const int skb0 = t & 7;
    const int kbs  = skb0 ^ (srow & 7);      // source col-chunk (XOR swizzle)
    // wave-uniform LDS dest: wave wv covers rows 8wv..8wv+7 (lane x 16B)
    const int ldst = wv * 512 * 8;           // shorts offset = wv*512; *8 inside macro below

// stage K tile N (64 rows of 64 f16) into Ks[B]; one pass, 512 threads
#define STAGE_K(N, B) \
    gload_lds16(kh + (size_t)((N) * 64 + srow) * 64 + kbs * 8, &Ks[B][wv * 512])

// stage V^T tile N (64 d-rows x 64 j) into Vs[B]; one pass
#define STAGE_V(N, B) \
    gload_lds16(vt + (size_t)srow * S_ + (N) * 64 + kbs * 8, &Vs[B][wv * 512])

// QK^T for one tile from Ks[KR] into SN (zeroed here):
// lane (lq,hf2) reg 4g+r of SN[jb] = S[q=lq][j = jb*32 + r + 8g + 4*hf2]
#define QK_STEP(SN, KR) do {                                                    \
    _Pragma("unroll")                                                           \
    for (int jb_ = 0; jb_ < 2; ++jb_)                                           \
        _Pragma("unroll")                                                       \
        for (int r_ = 0; r_ < 16; ++r_) SN[jb_][r_] = 0.f;                      \
    _Pragma("unroll")                                                           \
    for (int kk_ = 0; kk_ < 4; ++kk_)                                           \
        _Pragma("unroll")                                                       \
        for (int jb_ = 0; jb_ < 2; ++jb_) {                                     \
            const int row_ = jb_ * 32 + lq;                                     \
            const int cb_ = 2 * kk_ + hf2;                                      \
            const half8v kf_ = *(const half8v*)&Ks[KR][row_ * 64 + 8 * (cb_ ^ (row_ & 7))]; \
            SN[jb_] = __builtin_amdgcn_mfma_f32_32x32x16_f16(kf_, qf[kk_], SN[jb_], 0, 0, 0); \
        } } while (0)

// exp2(SC) -> pk (permuted-k A-frags), lsum; then PV from Vs[VR] into accO
#define SOFTMAX_PV(SC, VR) do {                                                 \
    unsigned pk_[2][4][2];                                                      \
    _Pragma("unroll")                                                           \
    for (int jb_ = 0; jb_ < 2; ++jb_)                                           \
        _Pragma("unroll")                                                       \
        for (int g_ = 0; g_ < 4; ++g_) {                                        \
            const float p0_ = fast_exp2(SC[jb_][4 * g_ + 0]);                   \
            const float p1_ = fast_exp2(SC[jb_][4 * g_ + 1]);                   \
            const float p2_ = fast_exp2(SC[jb_][4 * g_ + 2]);                   \
            const float p3_ = fast_exp2(SC[jb_][4 * g_ + 3]);                   \
            lsum += (p0_ + p1_) + (p2_ + p3_);                                  \
            pk_[jb_][g_][0] = pack_bf16_trunc(p0_, p1_);                        \
            pk_[jb_][g_][1] = pack_bf16_trunc(p2_, p3_);                        \
        }                                                                       \
    __builtin_amdgcn_s_setprio(1);                                              \
    _Pragma("unroll")                                                           \
    for (int jc_ = 0; jc_ < 4; ++jc_) {                                         \
        const int jb_ = jc_ >> 1, gg_ = (jc_ & 1) * 2;                          \
        const uint4 uu_ = {pk_[jb_][gg_][0], pk_[jb_][gg_][1],                  \
                           pk_[jb_][gg_ + 1][0], pk_[jb_][gg_ + 1][1]};         \
        const short8v pa_ = __builtin_bit_cast(short8v, uu_);                   \
        _Pragma("unroll")                                                       \
        for (int db_ = 0; db_ < 2; ++db_) {                                     \
            const int vrow_ = db_ * 32 + lq;                                    \
            const int cb_ = 2 * jc_ + hf2;                                      \
            const short8v vf_ = *(const short8v*)&Vs[VR][vrow_ * 64 + 8 * (cb_ ^ (vrow_ & 7))]; \
            accO[db_] = __builtin_amdgcn_mfma_f32_32x32x16_bf16(pa_, vf_, accO[db_], 0, 0, 0);  \
        }                                                                       \
    }                                                                           \
    __builtin_amdgcn_s_setprio(0);                                              \
} while (0)

    // prologue: stage K(0)->Ks[0], V(0)->Vs[0], K(1)->Ks[1]
    STAGE_K(0, 0);
    STAGE_V(0, 0);
    STAGE_K(1, 1);

    // Q B-frags: direct f16 load (pre-scaled by log2e in gemm_qkv);
    // lane holds Q[q = q0+wv*32+lq][d = kk*16 + hf2*8 + i]
    half8v qf[4];
    {
        const int qrow = q0 + wv * 32 + lq;
#pragma unroll
        for (int kk = 0; kk < 4; ++kk)
            qf[kk] = *(const half8v*)&qfp[(size_t)qrow * 64 + kk * 16 + hf2 * 8];
    }

    float16v accO[2];
#pragma unroll
    for (int db = 0; db < 2; ++db)
#pragma unroll
        for (int r = 0; r < 16; ++r) accO[db][r] = 0.f;
    float lsum = 0.f;

    float16v sA[2], sB[2];

    __syncthreads();            // K(0),V(0),K(1) DMA complete
    QK_STEP(sA, 0);             // QK(0) from Ks[0]
    __syncthreads();            // all waves done reading Ks[0] (no DMA pending)

    // Steady state, phases jt and jt+1 per loop iter (v7 schedule):
    for (int jt = 0; jt < 32; jt += 2) {
        // ---- even phase (jt) ----
        if (jt + 2 < 32) STAGE_K(jt + 2, 0);
        STAGE_V(jt + 1, 1);                    // jt+1 <= 31 always here
        QK_STEP(sB, 1);                        // QK(jt+1)
        SOFTMAX_PV(sA, 0);                     // exp2(jt) + PV(jt)
        __syncthreads();
        // ---- odd phase (jt+1) ----
        if (jt + 3 < 32) STAGE_K(jt + 3, 1);
        if (jt + 2 < 32) {
            STAGE_V(jt + 2, 0);
            QK_STEP(sA, 0);                    // QK(jt+2)
        }
        SOFTMAX_PV(sB, 1);                     // exp2(jt+1) + PV(jt+1)
        __syncthreads();
    }

#undef STAGE_K
#undef STAGE_V
#undef QK_STEP
#undef SOFTMAX_PV

    // lane holds l-partial for q=lq over its half of j; combine halves
    const float ls = lsum + __shfl_xor(lsum, 32);
    const float invl = 1.f / ls;

    // epilogue: accO[db][4g+r] = O[q_local=r+8g+4*hf2][d=db*32+lq]
    const int b = bh >> 3, hh = bh & 7;
#pragma unroll
    for (int g = 0; g < 4; ++g)
#pragma unroll
        for (int r = 0; r < 4; ++r) {
            const int qrow = r + 8 * g + 4 * hf2;
            const float inv = __shfl(invl, qrow);   // lane qrow holds q=qrow
            const int q = q0 + wv * 32 + qrow;
#pragma unroll
            for (int db = 0; db < 2; ++db)
                OB[((size_t)(b * 2048 + q)) * 512 + hh * 64 + db * 32 + lq] =
                    f2bf(accO[db][4 * g + r] * inv);
        }
}

// ---------------------------------------------------------------------------
// GEMM2 (out projection): 128x128 tile, BK=64, dbuf + prefetch, bijective
// XCD swizzle. Grid (4,64) = 256 blocks.
// ---------------------------------------------------------------------------
__global__ __launch_bounds__(256, 2) void gemm_out(const unsigned short* __restrict__ OB,
                                                   const unsigned short* __restrict__ Wob,
                                                   float* __restrict__ out) {
    __shared__ unsigned short Asm[2][128 * 64];   // 32 KB
    __shared__ unsigned short Bsm[2][128 * 64];   // 32 KB
    const int t = threadIdx.x, wv = t >> 6, lane = t & 63;
    const int fm = lane & 15, fq = lane >> 4;
    const int bid0 = blockIdx.x + 4 * blockIdx.y;
    const int xcd = bid0 & 7, ii = bid0 >> 3;    // ii in 0..31
    const int e0 = (ii % 4) * 128;
    const int m0 = ((ii / 4) * 8 + xcd) * 128;
    const int wrow = (wv >> 1) * 64, wcol = (wv & 1) * 64;

    const int srow = t >> 3;
    const int skb0 = t & 7;

    float4v acc[4][4];
#pragma unroll
    for (int i = 0; i < 4; ++i)
#pragma unroll
        for (int j = 0; j < 4; ++j) acc[i][j] = (float4v){0.f, 0.f, 0.f, 0.f};

    // prologue: stage k0=0
#pragma unroll
    for (int i = 0; i < 4; ++i) {
        const int row = srow + 32 * i;
        const int kb = skb0 ^ (row & 7);
        gload_lds16(OB + (size_t)(m0 + row) * 512 + kb * 8,
                    &Asm[0][(wv * 64 + 256 * i) * 8]);
        gload_lds16(Wob + (size_t)(e0 + row) * 512 + kb * 8,
                    &Bsm[0][(wv * 64 + 256 * i) * 8]);
    }

    for (int kk = 0; kk < 8; ++kk) {
        __syncthreads();
        if (kk + 1 < 8) {
            const int k0n = (kk + 1) * 64, nbuf = (kk + 1) & 1;
#pragma unroll
            for (int i = 0; i < 4; ++i) {
                const int row = srow + 32 * i;
                const int kb = skb0 ^ (row & 7);
                gload_lds16(OB + (size_t)(m0 + row) * 512 + k0n + kb * 8,
                            &Asm[nbuf][(wv * 64 + 256 * i) * 8]);
                gload_lds16(Wob + (size_t)(e0 + row) * 512 + k0n + kb * 8,
                            &Bsm[nbuf][(wv * 64 + 256 * i) * 8]);
            }
        }
        const int buf = kk & 1;
#pragma unroll
        for (int ks = 0; ks < 2; ++ks) {
            short8v af[4], bf[4];
#pragma unroll
            for (int mt = 0; mt < 4; ++mt) {
                const int row = wrow + mt * 16 + fm;
                af[mt] = *(const short8v*)&Asm[buf][row * 64 + 8 * ((4 * ks + fq) ^ (row & 7))];
            }
#pragma unroll
            for (int nt = 0; nt < 4; ++nt) {
                const int row = wcol + nt * 16 + fm;
                bf[nt] = *(const short8v*)&Bsm[buf][row * 64 + 8 * ((4 * ks + fq) ^ (row & 7))];
            }
#pragma unroll
            for (int mt = 0; mt < 4; ++mt)
#pragma unroll
                for (int nt = 0; nt < 4; ++nt)
                    acc[mt][nt] = __builtin_amdgcn_mfma_f32_16x16x32_bf16(af[mt], bf[nt], acc[mt][nt], 0, 0, 0);
        }
    }
#pragma unroll
    for (int mt = 0; mt < 4; ++mt)
#pragma unroll
        for (int nt = 0; nt < 4; ++nt)
#pragma unroll
            for (int r = 0; r < 4; ++r) {
                const int m = m0 + wrow + mt * 16 + 4 * fq + r;
                const int e = e0 + wcol + nt * 16 + fm;
                out[(size_t)m * 512 + e] = acc[mt][nt][r];
            }
}

// ---------------------------------------------------------------------------
extern "C" void kernel_launch(void* const* d_in, const int* in_sizes, int n_in,
                              void* d_out, int out_size, void* d_ws, size_t ws_size,
                              hipStream_t stream) {
    const float* x     = (const float*)d_in[0];   // [B,S,D]
    const float* w_qkv = (const float*)d_in[1];   // [3D, D]
    const float* w_out = (const float*)d_in[2];   // [D, D]
    float* out = (float*)d_out;                   // [B,S,D]

    // workspace carve-up (bytes): total ~36 MB
    char* p = (char*)d_ws;
    unsigned short* Xf  = (unsigned short*)p;  p += (size_t)M_ * 512 * 2;       // 8.4 MB (f16)
    unsigned short* Wf  = (unsigned short*)p;  p += (size_t)1536 * 512 * 2;     // 1.6 MB (f16)
    unsigned short* Wob = (unsigned short*)p;  p += (size_t)512 * 512 * 2;      // 0.5 MB (bf16)
    unsigned short* Qf  = (unsigned short*)p;  p += (size_t)32 * S_ * 64 * 2;   // 8.4 MB (f16, x log2e)
    unsigned short* KH  = (unsigned short*)p;  p += (size_t)32 * S_ * 64 * 2;   // 8.4 MB (f16)
    unsigned short* VT  = (unsigned short*)p;  p += (size_t)32 * 64 * S_ * 2;   // 8.4 MB (bf16, j-permuted)
    unsigned short* OB  = Xf;  // Xf dead after gemm_qkv; reuse for attention output

    prepass<<<2560, 256, 0, stream>>>(x, w_qkv, w_out, Xf, Wf, Wob);
    gemm_qkv<<<dim3(12, 64), 256, 0, stream>>>(Xf, Wf, Qf, KH, VT);
    attn<<<dim3(8, 32), 512, 0, stream>>>(Qf, KH, VT, OB);
    gemm_out<<<dim3(4, 64), 256, 0, stream>>>(OB, Wob, out);
}